// Round 2
// baseline (312.076 us; speedup 1.0000x reference)
//
#include <hip/hip_runtime.h>

#define NX 512
#define NY 512
#define XY (NX * NY)

typedef float f4 __attribute__((ext_vector_type(4)));

// Persistent-block cooperative version.
// 768 blocks (3/CU, LDS-limited: 48 KB) x 512 threads. Each block streams 5-6
// consecutive 4-row strips within one XCD's 4-batch region (L2 locality).
// Per strip: [ds_write staged regs] A [phase2: b rows + RETAIN s-fragments in
// registers; issue next strip's global loads] B [phase3: outputs from retained
// regs + 4x b128 of b_lds]. Global-load latency hides under phase2+phase3 of
// the previous strip (T14 issue-early/write-late). 2 barriers/strip:
//  - B(k) guarantees all phase2(k) s_lds reads done before s_lds write(k+1)
//  - A(k+1) guarantees all phase3(k) b_lds reads done before b_lds write(k+1)
__global__ __launch_bounds__(512, 6) void psi11t_kernel(
    const float* __restrict__ s,
    const float* __restrict__ t,
    const float* __restrict__ c0,
    float* __restrict__ out)
{
    __shared__ __align__(16) float s_lds[3 * 6 * NY];  // [c][row][y], row <-> x0-1+row
    __shared__ __align__(16) float b_lds[6 * NY];      // [row][y]

    const int tid = threadIdx.x;
    const int yb  = (tid & 127) * 4;
    const int r   = tid >> 7;                    // 0..3: output row within strip
    const int ybm = (yb + NY - 4) & (NY - 1);    // aligned f4 at y-4 (wrap)
    const int ybp = (yb + 4) & (NY - 1);         // aligned f4 at y+4 (wrap)
    const bool lo256 = (tid < 256);

    // Staging-slot constants: chunk k = tid + q*512 -> (comp, row, y). Hoisted.
    int sc[5], sr[5], sy[5];
    #pragma unroll
    for (int q = 0; q < 5; ++q) {
        const int k  = tid + q * 512;
        const int rl = k >> 7;                   // 0..17
        const int c  = rl / 6;
        sc[q] = c;
        sr[q] = rl - 6 * c;
        sy[q] = (k & 127) * 4;
    }

    // Work assignment: XCD = blockIdx&7 owns gids [xcd*512, xcd*512+512)
    // (4 whole batches). Block j = blockIdx>>3 takes a contiguous run.
    const int xcd = blockIdx.x & 7;
    const int j   = blockIdx.x >> 3;             // 0..95 within XCD
    const int cnt = (j < 32) ? 6 : 5;            // 32*6 + 64*5 = 512
    const int g0  = xcd * 512 + ((j < 32) ? 6 * j : 192 + 5 * (j - 32));

    const float coeff = 2.0f * t[0] * c0[0];

    f4 st[5], ge[3];

    // ---- prologue: issue loads for the first strip ----
    {
        const int bo = (g0 >> 7) * 3;
        const int x0 = (g0 & 127) * 4;
        #pragma unroll
        for (int q = 0; q < 4; ++q) {
            const int xg = (x0 - 1 + sr[q]) & (NX - 1);
            st[q] = *(const f4*)(s + (size_t)(bo + sc[q]) * XY + (size_t)xg * NY + sy[q]);
        }
        if (lo256) {
            const int xg4 = (x0 - 1 + sr[4]) & (NX - 1);
            st[4] = *(const f4*)(s + (size_t)(bo + sc[4]) * XY + (size_t)xg4 * NY + sy[4]);
            const int xe = (tid < 128) ? ((x0 - 2) & (NX - 1)) : ((x0 + 5) & (NX - 1));
            const float* re = s + (size_t)bo * XY + (size_t)xe * NY + yb;
            #pragma unroll
            for (int c = 0; c < 3; ++c) ge[c] = *(const f4*)(re + (size_t)c * XY);
        }
    }

    for (int i = 0; i < cnt; ++i) {
        const int gid = g0 + i;
        const int x0  = (gid & 127) * 4;
        const int bo  = (gid >> 7) * 3;

        // ---- stage to LDS (vmcnt-waits on loads issued a full strip ago) ----
        #pragma unroll
        for (int q = 0; q < 4; ++q)
            *(f4*)&s_lds[(size_t)(tid + q * 512) * 4] = st[q];
        if (lo256)
            *(f4*)&s_lds[(size_t)(tid + 2048) * 4] = st[4];
        __syncthreads();                         // A: s_lds ready, b_lds free

        // ---- phase 2: b rows 1..4 (all threads); retain s-fragments ----
        f4 ce[3], up[3], dn[3], shl[3], shr[3], Fs[3];
        f4 bc = {0.f, 0.f, 0.f, 0.f};
        #pragma unroll
        for (int c = 0; c < 3; ++c) {
            const float* S1 = &s_lds[(c * 6 + r + 1) * NY];
            up[c] = *(const f4*)&s_lds[(c * 6 + r) * NY + yb];
            ce[c] = *(const f4*)(S1 + yb);
            dn[c] = *(const f4*)&s_lds[(c * 6 + r + 2) * NY + yb];
            const f4 pv = *(const f4*)(S1 + ybm);
            const f4 nx = *(const f4*)(S1 + ybp);
            shl[c] = f4{pv[3], ce[c][0], ce[c][1], ce[c][2]};
            shr[c] = f4{ce[c][1], ce[c][2], ce[c][3], nx[0]};
            Fs[c]  = up[c] + dn[c] + shl[c] + shr[c];
            bc += ce[c] * Fs[c];
        }
        *(f4*)&b_lds[(r + 1) * NY + yb] = bc;

        // halo b rows 0 and 5 (waves 0-3; wave-uniform branches)
        if (lo256) {
            const int rb = (tid < 128) ? 0 : 5;
            const int ro = (tid < 128) ? 1 : 4;
            f4 acc = {0.f, 0.f, 0.f, 0.f};
            #pragma unroll
            for (int c = 0; c < 3; ++c) {
                const float* S0 = &s_lds[(c * 6 + rb) * NY];
                const f4 c2 = *(const f4*)(S0 + yb);
                const f4 p2 = *(const f4*)(S0 + ybm);
                const f4 n2 = *(const f4*)(S0 + ybp);
                const f4 ot = *(const f4*)&s_lds[(c * 6 + ro) * NY + yb];
                const f4 sl  = {p2[3], c2[0], c2[1], c2[2]};
                const f4 sr2 = {c2[1], c2[2], c2[3], n2[0]};
                acc += c2 * (ge[c] + ot + sl + sr2);
            }
            *(f4*)&b_lds[rb * NY + yb] = acc;
        }

        // ---- issue next strip's loads; latency hides under phase 3 ----
        if (i + 1 < cnt) {
            const int g1  = gid + 1;
            const int bo1 = (g1 >> 7) * 3;
            const int x1  = (g1 & 127) * 4;
            #pragma unroll
            for (int q = 0; q < 4; ++q) {
                const int xg = (x1 - 1 + sr[q]) & (NX - 1);
                st[q] = *(const f4*)(s + (size_t)(bo1 + sc[q]) * XY + (size_t)xg * NY + sy[q]);
            }
            if (lo256) {
                const int xg4 = (x1 - 1 + sr[4]) & (NX - 1);
                st[4] = *(const f4*)(s + (size_t)(bo1 + sc[4]) * XY + (size_t)xg4 * NY + sy[4]);
                const int xe = (tid < 128) ? ((x1 - 2) & (NX - 1)) : ((x1 + 5) & (NX - 1));
                const float* re = s + (size_t)bo1 * XY + (size_t)xe * NY + yb;
                #pragma unroll
                for (int c = 0; c < 3; ++c) ge[c] = *(const f4*)(re + (size_t)c * XY);
            }
        }

        __syncthreads();                         // B: b_lds ready

        // ---- phase 3: outputs from retained regs + b_lds ----
        const float* B1 = &b_lds[(r + 1) * NY];
        const f4 bu = *(const f4*)&b_lds[r * NY + yb];
        const f4 bd = *(const f4*)&b_lds[(r + 2) * NY + yb];
        const f4 bp = *(const f4*)(B1 + ybm);
        const f4 bn = *(const f4*)(B1 + ybp);
        const f4 bshl = {bp[3], bc[0], bc[1], bc[2]};
        const f4 bshr = {bc[1], bc[2], bc[3], bn[0]};

        f4 G[3];
        #pragma unroll
        for (int c = 0; c < 3; ++c)
            G[c] = Fs[c] * bc + up[c] * bu + dn[c] * bd + shl[c] * bshl + shr[c] * bshr;

        const f4 o0 = (ce[1] * G[2] - ce[2] * G[1]) * coeff;
        const f4 o1 = (ce[2] * G[0] - ce[0] * G[2]) * coeff;
        const f4 o2 = (ce[0] * G[1] - ce[1] * G[0]) * coeff;

        float* ob = out + (size_t)bo * XY + (size_t)(x0 + r) * NY + yb;
        __builtin_nontemporal_store(o0, (f4*)ob);
        __builtin_nontemporal_store(o1, (f4*)(ob + XY));
        __builtin_nontemporal_store(o2, (f4*)(ob + 2 * XY));
    }
}

extern "C" void kernel_launch(void* const* d_in, const int* in_sizes, int n_in,
                              void* d_out, int out_size, void* d_ws, size_t ws_size,
                              hipStream_t stream) {
    const float* s  = (const float*)d_in[0];
    const float* t  = (const float*)d_in[1];
    const float* c0 = (const float*)d_in[2];
    float* out = (float*)d_out;

    psi11t_kernel<<<768, 512, 0, stream>>>(s, t, c0, out);
}

// Round 3
// 179.115 us; speedup vs baseline: 1.7423x; 1.7423x over previous
//
#include <hip/hip_runtime.h>

#define NX 512
#define NY 512
#define XY (NX * NY)

typedef float f4 __attribute__((ext_vector_type(4)));

#define GLOBAL_AS __attribute__((address_space(1)))
#define LDS_AS    __attribute__((address_space(3)))

// Round-1 structure + three LDS-pipe cuts:
//  - stage via global_load_lds (16B DMA, linear dest = base + lane*16)
//  - phase 2 retains ce/up/dn f4 + 2 halo floats per comp (46 VGPRs) so
//    phase 3 never re-reads s from LDS (shl/shr are register renames)
//  - every LDS read is an aligned b128 (no 8-way-conflicted b32 reads)
// launch_bounds(512,4): VGPR cap 128 > ~115 peak -> NO SPILLS (round-2 lesson:
// (512,6) capped at 80 and generated 300 MB of scratch traffic).
__global__ __launch_bounds__(512, 4) void psi11t_kernel(
    const float* __restrict__ s,
    const float* __restrict__ t,
    const float* __restrict__ c0,
    float* __restrict__ out)
{
    __shared__ __align__(16) float s_lds[3 * 6 * NY];  // [c][row][y], row <-> x0-1+row
    __shared__ __align__(16) float b_lds[6 * NY];      // [row][y]

    // XCD swizzle: each XCD (D%8) gets 512 consecutive logical blocks = 4 whole
    // batches -> halo reuse stays within one XCD's L2.
    const int D = blockIdx.x;                 // 4096 blocks
    const int Lg = (D & 7) * 512 + (D >> 3);
    const int bidx  = Lg >> 7;                // 32 batches
    const int strip = Lg & 127;               // 128 strips of 4 rows
    const int x0  = strip * 4;
    const int tid = threadIdx.x;
    const int yb  = (tid & 127) * 4;
    const int r   = tid >> 7;                 // 0..3: output row within strip
    const int ybm = (yb + NY - 4) & (NY - 1); // aligned f4 at y-4 (wrap)
    const int ybp = (yb + 4) & (NY - 1);      // aligned f4 at y+4 (wrap)
    const bool lo256 = (tid < 256);

    const float* sb = s + (size_t)bidx * 3 * XY;

    // ---- Phase 1: stage 18 rows x 512 via global_load_lds (no VGPR round trip)
    // chunk k = tid + q*512 -> rl = (tid>>7) + 4q in 0..17 = c*6 + row
    #pragma unroll
    for (int q = 0; q < 4; ++q) {
        const int rl = r + 4 * q;
        const int c  = rl / 6;
        const int rr = rl - 6 * c;
        const int xg = (x0 - 1 + rr) & (NX - 1);
        const float* gp = sb + (size_t)c * XY + (size_t)xg * NY + (((tid + q * 512) & 127) * 4);
        __builtin_amdgcn_global_load_lds(
            (const GLOBAL_AS void*)gp,
            (LDS_AS void*)&s_lds[(size_t)(tid + q * 512) * 4], 16, 0, 0);
    }
    if (lo256) {
        const int rl = (tid >> 7) + 16;           // 16..17
        const int c  = rl / 6;                    // 2
        const int rr = rl - 6 * c;                // 4..5
        const int xg = (x0 - 1 + rr) & (NX - 1);
        const float* gp = sb + (size_t)c * XY + (size_t)xg * NY + ((tid & 127) * 4);
        __builtin_amdgcn_global_load_lds(
            (const GLOBAL_AS void*)gp,
            (LDS_AS void*)&s_lds[(size_t)(tid + 2048) * 4], 16, 0, 0);
    }

    // Outer halo rows (x0-2, x0+5) held in registers across the barrier.
    f4 ge[3];
    if (lo256) {
        const int xe = (tid < 128) ? ((x0 - 2) & (NX - 1)) : ((x0 + 5) & (NX - 1));
        const float* re = sb + (size_t)xe * NY + yb;
        #pragma unroll
        for (int c = 0; c < 3; ++c) ge[c] = *(const f4*)(re + (size_t)c * XY);
    }

    const float coeff = 2.0f * t[0] * c0[0];
    __syncthreads();                              // A: s_lds ready (vmcnt drained)

    // ---- Phase 2: b rows 1..4 (all threads); retain minimal s-fragments ----
    f4 ce[3], up[3], dn[3];
    float pv3[3], nx0[3];
    f4 bc = {0.f, 0.f, 0.f, 0.f};
    #pragma unroll
    for (int c = 0; c < 3; ++c) {
        const float* S1 = &s_lds[(c * 6 + r + 1) * NY];
        up[c] = *(const f4*)&s_lds[(c * 6 + r) * NY + yb];
        ce[c] = *(const f4*)(S1 + yb);
        dn[c] = *(const f4*)&s_lds[(c * 6 + r + 2) * NY + yb];
        const f4 pv = *(const f4*)(S1 + ybm);
        const f4 nx = *(const f4*)(S1 + ybp);
        pv3[c] = pv[3];
        nx0[c] = nx[0];
        const f4 shl = {pv[3], ce[c][0], ce[c][1], ce[c][2]};
        const f4 shr = {ce[c][1], ce[c][2], ce[c][3], nx[0]};
        bc += ce[c] * (up[c] + dn[c] + shl + shr);
    }
    *(f4*)&b_lds[(r + 1) * NY + yb] = bc;

    // halo b rows 0 and 5 (waves 0-3; wave-uniform branches, aligned reads only)
    if (lo256) {
        const int rb = (tid < 128) ? 0 : 5;
        const int ro = (tid < 128) ? 1 : 4;
        f4 acc = {0.f, 0.f, 0.f, 0.f};
        #pragma unroll
        for (int c = 0; c < 3; ++c) {
            const float* S0 = &s_lds[(c * 6 + rb) * NY];
            const f4 c2 = *(const f4*)(S0 + yb);
            const f4 p2 = *(const f4*)(S0 + ybm);
            const f4 n2 = *(const f4*)(S0 + ybp);
            const f4 ot = *(const f4*)&s_lds[(c * 6 + ro) * NY + yb];
            const f4 sl  = {p2[3], c2[0], c2[1], c2[2]};
            const f4 sr2 = {c2[1], c2[2], c2[3], n2[0]};
            acc += c2 * (ge[c] + ot + sl + sr2);
        }
        *(f4*)&b_lds[rb * NY + yb] = acc;
    }
    __syncthreads();                              // B: b_lds ready

    // ---- Phase 3: outputs from retained regs + 4x aligned b128 of b_lds ----
    const float* B1 = &b_lds[(r + 1) * NY];
    const f4 bu = *(const f4*)&b_lds[r * NY + yb];
    const f4 bd = *(const f4*)&b_lds[(r + 2) * NY + yb];
    const f4 bp = *(const f4*)(B1 + ybm);
    const f4 bn = *(const f4*)(B1 + ybp);
    const f4 bshl = {bp[3], bc[0], bc[1], bc[2]};
    const f4 bshr = {bc[1], bc[2], bc[3], bn[0]};

    f4 G[3];
    #pragma unroll
    for (int c = 0; c < 3; ++c) {
        const f4 shl = {pv3[c], ce[c][0], ce[c][1], ce[c][2]};
        const f4 shr = {ce[c][1], ce[c][2], ce[c][3], nx0[c]};
        const f4 Fs = up[c] + dn[c] + shl + shr;
        G[c] = Fs * bc + up[c] * bu + dn[c] * bd + shl * bshl + shr * bshr;
    }

    const f4 o0 = (ce[1] * G[2] - ce[2] * G[1]) * coeff;
    const f4 o1 = (ce[2] * G[0] - ce[0] * G[2]) * coeff;
    const f4 o2 = (ce[0] * G[1] - ce[1] * G[0]) * coeff;

    float* ob = out + (size_t)bidx * 3 * XY + (size_t)(x0 + r) * NY + yb;
    __builtin_nontemporal_store(o0, (f4*)ob);
    __builtin_nontemporal_store(o1, (f4*)(ob + XY));
    __builtin_nontemporal_store(o2, (f4*)(ob + 2 * XY));
}

extern "C" void kernel_launch(void* const* d_in, const int* in_sizes, int n_in,
                              void* d_out, int out_size, void* d_ws, size_t ws_size,
                              hipStream_t stream) {
    const float* s  = (const float*)d_in[0];
    const float* t  = (const float*)d_in[1];
    const float* c0 = (const float*)d_in[2];
    float* out = (float*)d_out;

    psi11t_kernel<<<4096, 512, 0, stream>>>(s, t, c0, out);
}